// Round 9
// baseline (167.944 us; speedup 1.0000x reference)
//
#include <hip/hip_runtime.h>

typedef unsigned short u16;
typedef unsigned int   u32;

#define NB 4
#define NT 4096
#define NC 512
#define NH 64
#define ATT_SCALE 0.044194173824159216f
#define NEG_BIG   -30000.0f

typedef __attribute__((ext_vector_type(8))) _Float16 half8;
typedef __attribute__((ext_vector_type(4))) _Float16 half4;
typedef __attribute__((ext_vector_type(4))) float    floatx4;

// Fragment-layout addressing: all MFMA operands live in 1KB blocks of 512
// halves; element (id, q4, j) at id*32 + q4*8 + j. A wave load for one
// operand is lane-offset id*32+quad*8 (halves) = one contiguous 1KB burst.

// ---------------------------------------------------------------------------
// Kernel 0: W (fp32) -> Wh' fragment layout [w][ks16][nt4]{1KB blocks};
// w: 0=q(ATT_SCALE folded), 1=k, 2=v.
// ---------------------------------------------------------------------------
__global__ __launch_bounds__(256) void wconv(
    const float* __restrict__ Wk, const float* __restrict__ Wq,
    const float* __restrict__ Wv, _Float16* __restrict__ Wh)
{
    const int gid = blockIdx.x * 256 + threadIdx.x;   // 24576 float4s
    const int w = gid >> 13;
    const int i = gid & 8191;                         // float4 within 64x512
    const int h = i >> 7, c = (i & 127) * 4;
    const float* src = (w == 0) ? Wq : (w == 1) ? Wk : Wv;
    const float sc = (w == 0) ? ATT_SCALE : 1.0f;
    float4 f = *(const float4*)&src[h * NC + c];
    half4 o = {(_Float16)(f.x * sc), (_Float16)(f.y * sc),
               (_Float16)(f.z * sc), (_Float16)(f.w * sc)};
    const int blk = ((w * 16 + (c >> 5)) * 4 + (h >> 4));
    *(half4*)&Wh[(size_t)blk * 512 + (h & 15) * 32 + ((c >> 3) & 3) * 8 + (c & 7)] = o;
}

// ---------------------------------------------------------------------------
// Kernel 1: q/k/v projection GEMM, 2-way k-split (unchanged from R8).
// Writes Q'/K'/V' fragment layouts.
// ---------------------------------------------------------------------------
__global__ __launch_bounds__(256) void qkv_mfma(
    const float* __restrict__ x, const _Float16* __restrict__ Wh,
    _Float16* __restrict__ Qf, _Float16* __restrict__ Kf,
    _Float16* __restrict__ Vf)
{
    __shared__ __align__(16) floatx4 red[2][12][64];  // 24 KB

    const int tid  = threadIdx.x;
    const int wv   = tid >> 6;
    const int lane = tid & 63;
    const int quad = lane >> 4;
    const int id   = lane & 15;
    const int rg   = wv >> 1, kh = wv & 1;
    const int rowbase = blockIdx.x * 32 + rg * 16;

    floatx4 acc[3][4] = {};
    const float* xp = x + (size_t)(rowbase + id) * NC + kh * 256;
    const int loff = id * 32 + quad * 8;

#pragma unroll
    for (int ks = 0; ks < 8; ++ks) {
        float4 f0 = *(const float4*)&xp[ks * 32 + quad * 8];
        float4 f1 = *(const float4*)&xp[ks * 32 + quad * 8 + 4];
        half8 a;
        a[0] = (_Float16)f0.x; a[1] = (_Float16)f0.y;
        a[2] = (_Float16)f0.z; a[3] = (_Float16)f0.w;
        a[4] = (_Float16)f1.x; a[5] = (_Float16)f1.y;
        a[6] = (_Float16)f1.z; a[7] = (_Float16)f1.w;
        const int ksg = kh * 8 + ks;
#pragma unroll
        for (int w = 0; w < 3; ++w)
#pragma unroll
            for (int nt = 0; nt < 4; ++nt) {
                half8 bf = *(const half8*)&Wh[(size_t)((w * 16 + ksg) * 4 + nt) * 512 + loff];
                acc[w][nt] = __builtin_amdgcn_mfma_f32_16x16x32_f16(a, bf, acc[w][nt], 0, 0, 0);
            }
    }

    if (kh == 1) {
#pragma unroll
        for (int w = 0; w < 3; ++w)
#pragma unroll
            for (int nt = 0; nt < 4; ++nt)
                red[rg][w * 4 + nt][lane] = acc[w][nt];
    }
    __syncthreads();
    if (kh == 1) return;

#pragma unroll
    for (int w = 0; w < 3; ++w)
#pragma unroll
        for (int nt = 0; nt < 4; ++nt)
            acc[w][nt] += red[rg][w * 4 + nt][lane];

    const int b  = rowbase >> 12, L = rowbase & 4095;
    const int q16 = L >> 4, kt = L >> 6, tt = (L >> 4) & 3;
    const int kop = ((rowbase & 63) + quad * 4) >> 5;
    const int q4k = ((((rowbase & 63) + quad * 4) >> 3) & 3);
#pragma unroll
    for (int nt = 0; nt < 4; ++nt) {
        const int hop = nt >> 1;
        const int q4h = (nt * 2 + (id >> 3)) & 3;
        const int j   = id & 7;
        const size_t qa = (size_t)((b * 256 + q16) * 2 + hop) * 512 + q4h * 8 + j;
        const size_t ka = (size_t)(((b * 64 + kt) * 4 + tt) * 2 + hop) * 512 + q4h * 8 + j;
#pragma unroll
        for (int r = 0; r < 4; ++r) {
            Qf[qa + (quad * 4 + r) * 32] = (_Float16)acc[0][nt][r];
            Kf[ka + (quad * 4 + r) * 32] = (_Float16)acc[1][nt][r];
        }
        half4 vh = {(_Float16)acc[2][nt][0], (_Float16)acc[2][nt][1],
                    (_Float16)acc[2][nt][2], (_Float16)acc[2][nt][3]};
        const size_t va = (size_t)(((b * 64 + kt) * 4 + nt) * 2 + kop) * 512
                        + id * 32 + q4k * 8 + (quad & 1) * 4;
        *(half4*)&Vf[va] = vh;
    }
}

// ---------------------------------------------------------------------------
// Kernel 2: fused attention, block-internal split-K (flash-decoding inside
// the block — NO global partials, no combine kernel). Block = 32 q-rows;
// its 4 waves each take a quarter of the causal k-range and run independent
// online-softmax flash (transposed: S^T = K Q^T, O^T = V^T P^T, per-lane
// state, contiguous 1KB fragment loads). Merge once at block end: m/l via
// LDS, fp32 atomicAdd into Osum, normalize, write out (fp32).
// Grid = 128 x 4 = 512 blocks = 2 blocks/CU, all co-resident. qt order
// alternates big/small so each CU gets a balanced pair.
// ---------------------------------------------------------------------------
__global__ __launch_bounds__(256, 4) void attn_fused(
    const _Float16* __restrict__ Qf, const _Float16* __restrict__ Kf,
    const _Float16* __restrict__ Vf, float* __restrict__ out)
{
    constexpr int KP = 72;
    __shared__ __align__(16) _Float16 Ps[4][2][16 * KP];   // 18.4 KB
    __shared__ __align__(16) float Osum[32][65];           // 8.3 KB (+1 pad)
    __shared__ float Mw[4][32], Lw[4][32];                 // 1 KB

    const int tid  = threadIdx.x;
    const int wv   = tid >> 6;
    const int lane = tid & 63;
    const int quad = lane >> 4;
    const int id   = lane & 15;
    const int i    = blockIdx.x;               // 0..127
    const int b    = blockIdx.y;
    const int qt   = (i & 1) ? (i >> 1) : (127 - (i >> 1));  // balance pairing
    const int loff = id * 32 + quad * 8;

    const int ntiles = (qt >> 1) + 1;          // causal k-tiles for rows qt*32..+31
    const int t0 = wv * ntiles / 4;
    const int t1 = (wv + 1) * ntiles / 4;      // wave's k-quarter (may be empty)

    // zero Osum (2080 floats); ordered before atomicAdds by the merge barrier
    for (int j = tid; j < 32 * 65; j += 256) ((float*)Osum)[j] = 0.f;

    // Q fragments (pre-scaled): 2 strips x 2 h-halves
    half8 qb[2][2];
#pragma unroll
    for (int s = 0; s < 2; ++s) {
        const size_t qa = (size_t)((b * 256 + qt * 2 + s) * 2) * 512 + loff;
        qb[s][0] = *(const half8*)&Qf[qa];
        qb[s][1] = *(const half8*)&Qf[qa + 512];
    }

    floatx4 o[2][4] = {};
    float m_i[2] = {NEG_BIG, NEG_BIG}, l_i[2] = {0.f, 0.f};

    for (int kt = t0; kt < t1; ++kt) {
        const size_t tb = (size_t)((b * 64 + kt) * 4) * 2 * 512;

        // S^T: A = K frags (1KB contiguous loads), B = Q frags
        floatx4 s4[2][4] = {};
#pragma unroll
        for (int t = 0; t < 4; ++t) {
            half8 ka0 = *(const half8*)&Kf[tb + (size_t)t * 1024 + loff];
            half8 ka1 = *(const half8*)&Kf[tb + (size_t)t * 1024 + 512 + loff];
            s4[0][t] = __builtin_amdgcn_mfma_f32_16x16x32_f16(ka0, qb[0][0], s4[0][t], 0, 0, 0);
            s4[0][t] = __builtin_amdgcn_mfma_f32_16x16x32_f16(ka1, qb[0][1], s4[0][t], 0, 0, 0);
            s4[1][t] = __builtin_amdgcn_mfma_f32_16x16x32_f16(ka0, qb[1][0], s4[1][t], 0, 0, 0);
            s4[1][t] = __builtin_amdgcn_mfma_f32_16x16x32_f16(ka1, qb[1][1], s4[1][t], 0, 0, 0);
        }

        // hoist half the V loads to overlap softmax latency
        half8 va[4][2];
#pragma unroll
        for (int t = 0; t < 2; ++t) {
            va[t][0] = *(const half8*)&Vf[tb + (size_t)t * 1024 + loff];
            va[t][1] = *(const half8*)&Vf[tb + (size_t)t * 1024 + 512 + loff];
        }

        if (kt == ntiles - 1) {                // diagonal tile: causal mask
            const int kb = kt * 64;
#pragma unroll
            for (int s = 0; s < 2; ++s) {
                const int qrow = qt * 32 + s * 16 + id;
#pragma unroll
                for (int t = 0; t < 4; ++t)
#pragma unroll
                    for (int r = 0; r < 4; ++r)
                        if (kb + 16 * t + quad * 4 + r > qrow)
                            s4[s][t][r] = NEG_BIG;
            }
        }

        // online softmax per strip: in-lane(16) + 2 shuffles
#pragma unroll
        for (int s = 0; s < 2; ++s) {
            float mx = s4[s][0][0];
#pragma unroll
            for (int t = 0; t < 4; ++t)
#pragma unroll
                for (int r = 0; r < 4; ++r) mx = fmaxf(mx, s4[s][t][r]);
            mx = fmaxf(mx, __shfl_xor(mx, 16));
            mx = fmaxf(mx, __shfl_xor(mx, 32));
            float mnew  = fmaxf(m_i[s], mx);
            float alpha = __expf(m_i[s] - mnew);
            m_i[s] = mnew;
            float psum = 0.f;
#pragma unroll
            for (int t = 0; t < 4; ++t)
#pragma unroll
                for (int r = 0; r < 4; ++r) {
                    float p = __expf(s4[s][t][r] - mnew);
                    s4[s][t][r] = p;
                    psum += p;
                }
            psum += __shfl_xor(psum, 16);
            psum += __shfl_xor(psum, 32);
            l_i[s] = l_i[s] * alpha + psum;

#pragma unroll
            for (int t = 0; t < 4; ++t) {
                half4 ph = {(_Float16)s4[s][t][0], (_Float16)s4[s][t][1],
                            (_Float16)s4[s][t][2], (_Float16)s4[s][t][3]};
                *(half4*)&Ps[wv][s][id * KP + 16 * t + quad * 4] = ph;
            }
#pragma unroll
            for (int t = 0; t < 4; ++t)
#pragma unroll
                for (int r = 0; r < 4; ++r) o[s][t][r] *= alpha;
        }

        // wave-private LDS round trip (lgkmcnt orders write->read)
        half8 pb[2][2];
#pragma unroll
        for (int s = 0; s < 2; ++s) {
            pb[s][0] = *(const half8*)&Ps[wv][s][id * KP + quad * 8];
            pb[s][1] = *(const half8*)&Ps[wv][s][id * KP + 32 + quad * 8];
        }

#pragma unroll
        for (int t = 2; t < 4; ++t) {
            va[t][0] = *(const half8*)&Vf[tb + (size_t)t * 1024 + loff];
            va[t][1] = *(const half8*)&Vf[tb + (size_t)t * 1024 + 512 + loff];
        }
#pragma unroll
        for (int t = 0; t < 4; ++t) {
            o[0][t] = __builtin_amdgcn_mfma_f32_16x16x32_f16(va[t][0], pb[0][0], o[0][t], 0, 0, 0);
            o[0][t] = __builtin_amdgcn_mfma_f32_16x16x32_f16(va[t][1], pb[0][1], o[0][t], 0, 0, 0);
            o[1][t] = __builtin_amdgcn_mfma_f32_16x16x32_f16(va[t][0], pb[1][0], o[1][t], 0, 0, 0);
            o[1][t] = __builtin_amdgcn_mfma_f32_16x16x32_f16(va[t][1], pb[1][1], o[1][t], 0, 0, 0);
        }
    }

    // ---- block-level merge (once per block) ----
    if (quad == 0) {
#pragma unroll
        for (int s = 0; s < 2; ++s) {
            Mw[wv][s * 16 + id] = m_i[s];
            Lw[wv][s * 16 + id] = l_i[s];
        }
    }
    __syncthreads();   // orders Osum zeroing + Mw/Lw writes before adds

#pragma unroll
    for (int s = 0; s < 2; ++s) {
        const int row = s * 16 + id;
        float M = fmaxf(fmaxf(Mw[0][row], Mw[1][row]), fmaxf(Mw[2][row], Mw[3][row]));
        float w = __expf(m_i[s] - M);          // 0 for empty waves
#pragma unroll
        for (int t = 0; t < 4; ++t)
#pragma unroll
            for (int r = 0; r < 4; ++r)
                atomicAdd(&Osum[row][16 * t + quad * 4 + r], o[s][t][r] * w);
    }
    __syncthreads();

    // writeout: thread = (row, 8-col chunk); normalize by L
    const int row = tid >> 3, hc = tid & 7;
    float M = fmaxf(fmaxf(Mw[0][row], Mw[1][row]), fmaxf(Mw[2][row], Mw[3][row]));
    float L = Lw[0][row] * __expf(Mw[0][row] - M) + Lw[1][row] * __expf(Mw[1][row] - M)
            + Lw[2][row] * __expf(Mw[2][row] - M) + Lw[3][row] * __expf(Mw[3][row] - M);
    const float rl = 1.f / L;
    float* dst = out + (size_t)(b * NT + qt * 32 + row) * NH + hc * 8;
    float4 o0 = make_float4(Osum[row][hc * 8 + 0] * rl, Osum[row][hc * 8 + 1] * rl,
                            Osum[row][hc * 8 + 2] * rl, Osum[row][hc * 8 + 3] * rl);
    float4 o1 = make_float4(Osum[row][hc * 8 + 4] * rl, Osum[row][hc * 8 + 5] * rl,
                            Osum[row][hc * 8 + 6] * rl, Osum[row][hc * 8 + 7] * rl);
    *(float4*)dst = o0;
    *(float4*)(dst + 4) = o1;
}

extern "C" void kernel_launch(void* const* d_in, const int* in_sizes, int n_in,
                              void* d_out, int out_size, void* d_ws, size_t ws_size,
                              hipStream_t stream) {
    const float* x  = (const float*)d_in[0];
    const float* Wk = (const float*)d_in[1];
    const float* Wq = (const float*)d_in[2];
    const float* Wv = (const float*)d_in[3];

    // ws layout (6.5 MB): Qf/Kf/Vf 3x2MB | Wh 192KB
    char* wsb = (char*)d_ws;
    _Float16* Qf = (_Float16*)wsb;
    _Float16* Kf = Qf + 1048576;
    _Float16* Vf = Kf + 1048576;
    _Float16* Wh = Vf + 1048576;

    wconv<<<96, 256, 0, stream>>>(Wk, Wq, Wv, Wh);
    qkv_mfma<<<512, 256, 0, stream>>>(x, Wh, Qf, Kf, Vf);
    attn_fused<<<dim3(128, NB), 256, 0, stream>>>(Qf, Kf, Vf, (float*)d_out);
}